// Round 1
// 196.822 us; speedup vs baseline: 1.0262x; 1.0262x over previous
//
#include <hip/hip_runtime.h>
#include <stdint.h>

// QuantizedConv2d int8 implicit GEMM via MFMA i32_16x16x64_i8.
// N=32, C_in=128, H=W=56, C_out=256, 3x3, pad 1, stride 1.
// Output int8 values stored as int32 (harness reads integer outputs as np.int32).
//
// R11: persistent-block pipeline. 256 blocks (1/CU), each owns (n, co64) and
// 3-4 of the 7 eight-row slabs. B (72 KB) staged once per block. A slab s+1 is
// prefetched into registers (20 x v4i/thread) before the K-loop of slab s and
// committed to LDS via ds_write after a raw s_barrier (no vmcnt(0) drain of the
// output stores). Epilogue stores acc directly (64-B line coverage via quads),
// dropping the LDS transpose and its extra barrier. XCD swizzle: bid&7 -> XCD,
// so each XCD's 32 blocks touch only 4 n-images of xp2 (1.86 MB, L2-resident).

#define NB 32
#define CI 128
#define HH 56
#define WW 56
#define CO 256
#define SPA (HH * WW)              // 3136 = 7 blocks x 448 (8 image rows each)
#define HP 58
#define WP 64
#define XP2_BYTES (NB * HP * WP * CI)      // 15204352
#define BP_BYTES (9 * 2 * 4 * CO * 16)     // 294912

typedef int v4i __attribute__((ext_vector_type(4)));

// ---- prep (unchanged from R10) ----
// [0,1792): pack one (n,h) row -> padded NHWC int8, pad byte = zp, XOR-swizzled
// [1792,1856): border h-rows = zp
// [1856,2112): weight pack + BG[co] = bias - zp*S9
__global__ __launch_bounds__(256) void prep_kernel(
    const int* __restrict__ x, const int* __restrict__ wgt,
    const int* __restrict__ bias, const int* __restrict__ zpi,
    int8_t* __restrict__ xp2, int8_t* __restrict__ bp, int* __restrict__ BG)
{
    __shared__ int sm[1824];
    const int tid = threadIdx.x, bid = blockIdx.x;
    const int zp = *zpi;
    const int zp4 = (zp & 255) * 0x01010101;

    if (bid < HH * NB) {
        const int n = bid / HH, h = bid % HH;
        #pragma unroll
        for (int it = 0; it < 7; ++it) {
            int j = tid + it * 256;                 // 1792 = 128 ci x 14 w4
            int ci = j / 14, w4 = j - ci * 14;
            const v4i v = *(const v4i*)(x + ((n * CI + ci) * HH + h) * WW + w4 * 4);
            sm[w4 * 130 + ci] = (v.x & 255) | ((v.y & 255) << 8) |
                                ((v.z & 255) << 16) | (v.w << 24);
        }
        __syncthreads();
        int* od = (int*)xp2 + (n * HP + h + 1) * (WP * CI / 4);  // 2048 dwords
        #pragma unroll
        for (int it = 0; it < 8; ++it) {
            int j = tid + it * 256;                 // j = widx*32 + ci4
            int widx = j >> 5, ci4 = j & 31;
            int val = zp4;                          // pad value = zp
            if (widx >= 1 && widx <= WW) {
                int w = widx - 1;
                int base = (w >> 2) * 130 + ci4 * 4;
                int sh = (w & 3) * 8;
                val = ((sm[base] >> sh) & 0xff) | (((sm[base+1] >> sh) & 0xff) << 8) |
                      (((sm[base+2] >> sh) & 0xff) << 16) | ((sm[base+3] >> sh) << 24);
            }
            od[j ^ ((widx & 7) << 2)] = val;        // XOR-swizzle 16-B units
        }
    } else if (bid < HH * NB + 2 * NB) {
        const int z = bid - HH * NB;
        const int n = z >> 1, hidx = (z & 1) ? (HP - 1) : 0;
        int* od = (int*)xp2 + (n * HP + hidx) * (WP * CI / 4);
        #pragma unroll
        for (int it = 0; it < 8; ++it) od[tid + it * 256] = zp4;  // zp border rows
    } else {
        const int co = bid - (HH * NB + 2 * NB);
        for (int j = tid; j < 1152; j += 256) sm[j] = wgt[co * 1152 + j];  // [ci][9]
        __syncthreads();
        for (int j = tid; j < 288; j += 256) {      // 9t x 2c64 x 4q x 4j4
            int j4 = j & 3, q = (j >> 2) & 3, c64 = (j >> 4) & 1, t = j >> 5;
            int ci = c64 * 64 + q * 16 + j4 * 4;
            int b0 = sm[(ci + 0) * 9 + t] & 255, b1 = sm[(ci + 1) * 9 + t] & 255;
            int b2 = sm[(ci + 2) * 9 + t] & 255, b3 = sm[(ci + 3) * 9 + t];
            ((int*)bp)[((t * 2 + c64) * 4 + q) * 1024 + co * 4 + j4] =
                b0 | (b1 << 8) | (b2 << 16) | (b3 << 24);
        }
        if (tid < 9) {
            int s = 0;
            for (int ci = 0; ci < CI; ++ci) s += sm[ci * 9 + tid];
            sm[1152 + tid] = s;
        }
        __syncthreads();
        if (tid == 0) {
            int s9 = 0;
            for (int t = 0; t < 9; ++t) s9 += sm[1152 + t];
            BG[co] = bias[co] - zp * s9;            // cls-independent correction
        }
    }
}

// ---- main: 256 persistent blocks, each (n, co64, slab-parity) ----
// per block: stage B once; loop 3-4 slabs with reg-staged A double buffer.
__global__ __launch_bounds__(256, 1) void qconv_mfma(
    const int8_t* __restrict__ xp2, const int8_t* __restrict__ bp,
    const int* __restrict__ BG,
    const float* __restrict__ si, const float* __restrict__ sw,
    const float* __restrict__ so, const int* __restrict__ zpo,
    int* __restrict__ out)
{
    const int tid  = threadIdx.x, lane = tid & 63, wid = tid >> 6;
    const int quad = lane >> 4, lo16 = lane & 15;
    const int bid  = blockIdx.x;                    // 256 blocks, 1 per CU
    // XCD swizzle: x = XCD. Each XCD gets 16 cols (4 complete n) x 2 halves.
    const int x    = bid & 7, yb = bid >> 3;
    const int half = yb >> 4, coli = yb & 15;
    const int col  = x * 16 + coli;                 // 0..127 = (n, co64)
    const int n = col >> 2, co64 = col & 3;
    const int cobase = co64 * 64;
    const int sfirst = half;                        // slabs sfirst, sfirst+2, ...
    const int ntiles = half ? 3 : 4;                // even: 0,2,4,6  odd: 1,3,5

    __shared__ __attribute__((aligned(16))) char smem[152 * 1024];
    char* Asm = smem;                               // 80 KB A slab (10 rows)
    char* Bsm = smem + 80 * 1024;                   // 72 KB B (resident)

    #pragma unroll
    for (int k = 0; k < 18; ++k) {                  // B: 72 x 1-KB units, once
        const int u = wid + 4 * k;
        __builtin_amdgcn_global_load_lds(
            (const __attribute__((address_space(1))) void*)(bp + (u << 12) + cobase * 16 + lane * 16),
            (__attribute__((address_space(3))) void*)(Bsm + (u << 10)), 16, 0, 0);
    }
    const int8_t* aslab0 = xp2 + (((size_t)n * HP + sfirst * 8) << 13);
    #pragma unroll
    for (int k = 0; k < 20; ++k) {                  // first A slab: 80 x 1-KB
        const int u = wid + 4 * k;
        __builtin_amdgcn_global_load_lds(
            (const __attribute__((address_space(1))) void*)(aslab0 + (u << 10) + lane * 16),
            (__attribute__((address_space(3))) void*)(Asm + (u << 10)), 16, 0, 0);
    }

    int abase[7];
    const int mw = wid * 112;
    #pragma unroll
    for (int mt = 0; mt < 7; ++mt) {                // slab-local addr, tap (0,0)
        const int ml = mw + mt * 16 + lo16;         // 0..447
        const int srow = ml / 56, scol = ml - srow * 56;
        abase[mt] = (srow * WP + scol) * 128 + quad * 16;
    }

    int bgv[4];
    #pragma unroll
    for (int ct = 0; ct < 4; ++ct) bgv[ct] = BG[cobase + ct * 16 + lo16];
    const float rs = (*si) * (*sw) / (*so);
    const float zo = (float)(*zpo);

    int* optr = out + (n * CO + cobase + lo16) * SPA + mw + quad * 4;

    __syncthreads();                                // prologue staging drained

    for (int tile = 0; tile < ntiles; ++tile) {
        const int slab = sfirst + 2 * tile;
        const int havenext = (tile + 1 < ntiles);

        // ---- issue reg-prefetch of next A slab (hides under K-loop) ----
        v4i pre[20];
        if (havenext) {
            const int8_t* anext = xp2 + (((size_t)n * HP + (slab + 2) * 8) << 13);
            #pragma unroll
            for (int i = 0; i < 20; ++i)
                pre[i] = *(const v4i*)(anext + i * 4096 + tid * 16);
        }

        v4i acc[7][4];
        #pragma unroll
        for (int mt = 0; mt < 7; ++mt)
            #pragma unroll
            for (int ct = 0; ct < 4; ++ct) acc[mt][ct] = (v4i){0, 0, 0, 0};

        #pragma unroll
        for (int t = 0; t < 9; ++t) {
            const int toff = ((t / 3) * WP + (t % 3)) * 128;
            v4i b[2][4];                            // B for this tap -> registers
            #pragma unroll
            for (int c = 0; c < 2; ++c)
                #pragma unroll
                for (int ct = 0; ct < 4; ++ct)
                    b[c][ct] = *(const v4i*)(Bsm + ((t * 2 + c) * 4 + quad) * 1024 +
                                             lo16 * 16 + ct * 256);
            #pragma unroll
            for (int mt = 0; mt < 7; ++mt) {
                const int P = abase[mt] + toff;     // bit 6 of P is always 0
                const int phys = P ^ (((P >> 7) & 7) << 4);   // match prep swizzle
                v4i a0 = *(const v4i*)(Asm + phys);           // logical ci 0..63
                v4i a1 = *(const v4i*)(Asm + (phys ^ 64));    // logical P+64 -> phys^64
                #pragma unroll
                for (int ct = 0; ct < 4; ++ct)
                    acc[mt][ct] = __builtin_amdgcn_mfma_i32_16x16x64_i8(a0, b[0][ct], acc[mt][ct], 0, 0, 0);
                #pragma unroll
                for (int ct = 0; ct < 4; ++ct)
                    acc[mt][ct] = __builtin_amdgcn_mfma_i32_16x16x64_i8(a1, b[1][ct], acc[mt][ct], 0, 0, 0);
            }
        }

        // ---- B1: all waves done reading A slab (ds_reads consumed by MFMAs,
        //      so lgkm is drained per-wave by data-dep before arrival) ----
        __builtin_amdgcn_sched_barrier(0);
        __builtin_amdgcn_s_barrier();
        __builtin_amdgcn_sched_barrier(0);

        // commit next A slab (overlaps requant VALU below; compiler inserts
        // the exact vmcnt for pre[] readiness)
        if (havenext) {
            #pragma unroll
            for (int i = 0; i < 20; ++i)
                *(v4i*)(Asm + i * 4096 + tid * 16) = pre[i];
        }

        // ---- epilogue: requant + direct stores (no LDS, no extra barrier).
        //      quads cover m in 16-B steps -> full 64-B lines per co. ----
        const int sbase = slab * 448;
        #pragma unroll
        for (int mt = 0; mt < 7; ++mt) {
            #pragma unroll
            for (int ct = 0; ct < 4; ++ct) {
                v4i vv;
                #pragma unroll
                for (int i = 0; i < 4; ++i) {       // C/D row = quad*4+i
                    float yv = rintf((float)(acc[mt][ct][i] + bgv[ct]) * rs + zo);
                    yv = fminf(fmaxf(yv, -128.f), 127.f);
                    vv[i] = (int)yv;
                }
                *(v4i*)(optr + sbase + ct * 16 * SPA + mt * 16) = vv;
            }
        }

        // ---- B2: new A slab visible; stores stay in flight (no vmcnt drain) ----
        if (havenext) {
            asm volatile("s_waitcnt lgkmcnt(0)" ::: "memory");
            __builtin_amdgcn_sched_barrier(0);
            __builtin_amdgcn_s_barrier();
            __builtin_amdgcn_sched_barrier(0);
        }
    }
}

extern "C" void kernel_launch(void* const* d_in, const int* in_sizes, int n_in,
                              void* d_out, int out_size, void* d_ws, size_t ws_size,
                              hipStream_t stream) {
    const int*   x    = (const int*)d_in[0];
    const int*   wgt  = (const int*)d_in[1];
    const int*   bias = (const int*)d_in[2];
    const float* si   = (const float*)d_in[3];
    const float* sw   = (const float*)d_in[4];
    const float* so   = (const float*)d_in[5];
    const int*   zpi  = (const int*)d_in[6];
    const int*   zpo  = (const int*)d_in[7];
    int* out = (int*)d_out;

    int8_t* xp2 = (int8_t*)d_ws;
    int8_t* bp  = xp2 + XP2_BYTES;
    int*    bg  = (int*)(bp + BP_BYTES);

    prep_kernel<<<HH * NB + 2 * NB + CO, 256, 0, stream>>>(x, wgt, bias, zpi, xp2, bp, bg);
    qconv_mfma<<<256, 256, 0, stream>>>(xp2, bp, bg, si, sw, so, zpo, out);
}

// Round 2
// 187.416 us; speedup vs baseline: 1.0777x; 1.0502x over previous
//
#include <hip/hip_runtime.h>
#include <stdint.h>

// QuantizedConv2d int8 implicit GEMM via MFMA i32_16x16x64_i8.
// N=32, C_in=128, H=W=56, C_out=256, 3x3, pad 1, stride 1.
// Output int8 values stored as int32 (harness reads integer outputs as np.int32).
//
// R12: balanced persistent pipeline.
//  - 1792 tiles = 32 n x 14 four-row slabs x 4 co64; 256 blocks x 7 tiles each
//    (R11's 4-vs-3 tile imbalance eliminated).
//  - B lives in registers (36 v4i per wave, loaded once from bp); LDS holds a
//    true 2 x 48 KB A double buffer (96 KB).
//  - A slab s+2 staged via global_load_lds into the idle buffer BEFORE the
//    K-loop of slab s; released by counted s_waitcnt vmcnt(14) (14 = this
//    tile's stores, issued after the loads) + raw s_barrier. Loads hide under
//    252 MFMAs; stores are never drained (no vmcnt(0) in the loop).
//  - Wave = 112 M x 32 co (7 mt x 2 ct); 4 MFMA per ds_read pair.
//  - XCD swizzle: bid&7 = XCD; each XCD owns 4 n-images (1.9 MB xp2 + bp in L2).

#define NB 32
#define CI 128
#define HH 56
#define WW 56
#define CO 256
#define SPA (HH * WW)              // 3136 = 14 slabs x 224 (4 image rows each)
#define HP 58
#define WP 64
#define XP2_BYTES (NB * HP * WP * CI)      // 15204352
#define BP_BYTES (9 * 2 * 4 * CO * 16)     // 294912
#define ABUF (6 * 8192)                    // 6 padded rows = 48 KB

typedef int v4i __attribute__((ext_vector_type(4)));

// ---- prep (unchanged from R10) ----
// [0,1792): pack one (n,h) row -> padded NHWC int8, pad byte = zp, XOR-swizzled
// [1792,1856): border h-rows = zp
// [1856,2112): weight pack + BG[co] = bias - zp*S9
__global__ __launch_bounds__(256) void prep_kernel(
    const int* __restrict__ x, const int* __restrict__ wgt,
    const int* __restrict__ bias, const int* __restrict__ zpi,
    int8_t* __restrict__ xp2, int8_t* __restrict__ bp, int* __restrict__ BG)
{
    __shared__ int sm[1824];
    const int tid = threadIdx.x, bid = blockIdx.x;
    const int zp = *zpi;
    const int zp4 = (zp & 255) * 0x01010101;

    if (bid < HH * NB) {
        const int n = bid / HH, h = bid % HH;
        #pragma unroll
        for (int it = 0; it < 7; ++it) {
            int j = tid + it * 256;                 // 1792 = 128 ci x 14 w4
            int ci = j / 14, w4 = j - ci * 14;
            const v4i v = *(const v4i*)(x + ((n * CI + ci) * HH + h) * WW + w4 * 4);
            sm[w4 * 130 + ci] = (v.x & 255) | ((v.y & 255) << 8) |
                                ((v.z & 255) << 16) | (v.w << 24);
        }
        __syncthreads();
        int* od = (int*)xp2 + (n * HP + h + 1) * (WP * CI / 4);  // 2048 dwords
        #pragma unroll
        for (int it = 0; it < 8; ++it) {
            int j = tid + it * 256;                 // j = widx*32 + ci4
            int widx = j >> 5, ci4 = j & 31;
            int val = zp4;                          // pad value = zp
            if (widx >= 1 && widx <= WW) {
                int w = widx - 1;
                int base = (w >> 2) * 130 + ci4 * 4;
                int sh = (w & 3) * 8;
                val = ((sm[base] >> sh) & 0xff) | (((sm[base+1] >> sh) & 0xff) << 8) |
                      (((sm[base+2] >> sh) & 0xff) << 16) | ((sm[base+3] >> sh) << 24);
            }
            od[j ^ ((widx & 7) << 2)] = val;        // XOR-swizzle 16-B units
        }
    } else if (bid < HH * NB + 2 * NB) {
        const int z = bid - HH * NB;
        const int n = z >> 1, hidx = (z & 1) ? (HP - 1) : 0;
        int* od = (int*)xp2 + (n * HP + hidx) * (WP * CI / 4);
        #pragma unroll
        for (int it = 0; it < 8; ++it) od[tid + it * 256] = zp4;  // zp border rows
    } else {
        const int co = bid - (HH * NB + 2 * NB);
        for (int j = tid; j < 1152; j += 256) sm[j] = wgt[co * 1152 + j];  // [ci][9]
        __syncthreads();
        for (int j = tid; j < 288; j += 256) {      // 9t x 2c64 x 4q x 4j4
            int j4 = j & 3, q = (j >> 2) & 3, c64 = (j >> 4) & 1, t = j >> 5;
            int ci = c64 * 64 + q * 16 + j4 * 4;
            int b0 = sm[(ci + 0) * 9 + t] & 255, b1 = sm[(ci + 1) * 9 + t] & 255;
            int b2 = sm[(ci + 2) * 9 + t] & 255, b3 = sm[(ci + 3) * 9 + t];
            ((int*)bp)[((t * 2 + c64) * 4 + q) * 1024 + co * 4 + j4] =
                b0 | (b1 << 8) | (b2 << 16) | (b3 << 24);
        }
        if (tid < 9) {
            int s = 0;
            for (int ci = 0; ci < CI; ++ci) s += sm[ci * 9 + tid];
            sm[1152 + tid] = s;
        }
        __syncthreads();
        if (tid == 0) {
            int s9 = 0;
            for (int t = 0; t < 9; ++t) s9 += sm[1152 + t];
            BG[co] = bias[co] - zp * s9;            // cls-independent correction
        }
    }
}

// ---- main: 256 blocks x 256 thr; block = (n, co64, parity), 7 tiles ----
__global__ __launch_bounds__(256, 1) void qconv_mfma(
    const int8_t* __restrict__ xp2, const int8_t* __restrict__ bp,
    const int* __restrict__ BG,
    const float* __restrict__ si, const float* __restrict__ sw,
    const float* __restrict__ so, const int* __restrict__ zpo,
    int* __restrict__ out)
{
    const int tid  = threadIdx.x, lane = tid & 63, wid = tid >> 6;
    const int quad = lane >> 4, lo16 = lane & 15;
    const int bid  = blockIdx.x;                    // 256 blocks, 1 per CU
    const int x    = bid & 7, r = bid >> 3;         // x = XCD
    const int n    = x * 4 + (r & 3);               // 4 n-images per XCD
    const int co64 = (r >> 2) & 3;
    const int p    = r >> 4;                        // slab parity
    const int mh   = wid >> 1, ch = wid & 1;        // wave: m-half x co-half
    const int cw   = co64 * 64 + ch * 32;           // wave co base (32 co)

    __shared__ __attribute__((aligned(16))) int8_t Asm[2][ABUF];  // 96 KB

    // ---- prologue: stage slab p (6 padded rows, 48 KB) into buf0 ----
    const int8_t* src0 = xp2 + (((size_t)n * HP + 4 * p) << 13);
    #pragma unroll
    for (int k = 0; k < 12; ++k) {
        const int u = wid + 4 * k;                  // 48 x 1-KB units
        __builtin_amdgcn_global_load_lds(
            (const __attribute__((address_space(1))) void*)(src0 + (u << 10) + lane * 16),
            (__attribute__((address_space(3))) void*)(&Asm[0][u << 10]), 16, 0, 0);
    }

    // ---- B -> registers: breg[tap][c64][ct], 36 v4i (whole co32 panel) ----
    v4i breg[9][2][2];
    #pragma unroll
    for (int t = 0; t < 9; ++t)
        #pragma unroll
        for (int c = 0; c < 2; ++c)
            #pragma unroll
            for (int ct = 0; ct < 2; ++ct)
                breg[t][c][ct] = *(const v4i*)(bp + (((t * 2 + c) * 4 + quad) << 12) +
                                               (cw + ct * 16 + lo16) * 16);

    int bgv[2];
    #pragma unroll
    for (int ct = 0; ct < 2; ++ct) bgv[ct] = BG[cw + ct * 16 + lo16];
    const float rs = (*si) * (*sw) / (*so);
    const float zo = (float)(*zpo);

    // per-mt geometry (slab-local): row offset + swizzled col part per tap-col
    int rowoff[7], colp[7][3];
    #pragma unroll
    for (int mt = 0; mt < 7; ++mt) {
        const int ml = mh * 112 + mt * 16 + lo16;   // 0..223 within slab
        const int srow = ml / 56, scol = ml - srow * 56;
        rowoff[mt] = srow * 8192;
        #pragma unroll
        for (int dc = 0; dc < 3; ++dc) {
            const int c2 = scol + dc;               // padded col 0..57
            colp[mt][dc] = (c2 * 128 + quad * 16) ^ ((c2 & 7) << 4);
        }
    }

    __syncthreads();                                // buf0 staged (vmcnt(0) here is fine: prologue only)

    #pragma unroll 1
    for (int t7 = 0; t7 < 7; ++t7) {
        const int s = p + 2 * t7;                   // slab 0..13
        const int8_t* curA = Asm[t7 & 1];

        // ---- issue async stage of slab s+2 into the idle buffer ----
        if (t7 < 6) {
            const int8_t* srcn = xp2 + (((size_t)n * HP + 4 * (s + 2)) << 13);
            int8_t* dst = (int8_t*)Asm[(t7 & 1) ^ 1];
            #pragma unroll
            for (int k = 0; k < 12; ++k) {
                const int u = wid + 4 * k;
                __builtin_amdgcn_global_load_lds(
                    (const __attribute__((address_space(1))) void*)(srcn + (u << 10) + lane * 16),
                    (__attribute__((address_space(3))) void*)(dst + (u << 10)), 16, 0, 0);
            }
        }
        __builtin_amdgcn_sched_barrier(0);          // pin load issue before K-loop

        v4i acc[7][2];
        #pragma unroll
        for (int mt = 0; mt < 7; ++mt)
            #pragma unroll
            for (int ct = 0; ct < 2; ++ct) acc[mt][ct] = (v4i){0, 0, 0, 0};

        // ---- K-loop: 9 taps x 7 mt x (2 reads + 4 MFMA) ----
        #pragma unroll
        for (int tp = 0; tp < 9; ++tp) {
            const int dr = tp / 3, dc = tp % 3;
            #pragma unroll
            for (int mt = 0; mt < 7; ++mt) {
                const int off = rowoff[mt] + dr * 8192 + colp[mt][dc];
                v4i a0 = *(const v4i*)(curA + off);          // logical ci 0..63
                v4i a1 = *(const v4i*)(curA + (off ^ 64));   // logical +64 -> phys^64
                acc[mt][0] = __builtin_amdgcn_mfma_i32_16x16x64_i8(a0, breg[tp][0][0], acc[mt][0], 0, 0, 0);
                acc[mt][1] = __builtin_amdgcn_mfma_i32_16x16x64_i8(a0, breg[tp][0][1], acc[mt][1], 0, 0, 0);
                acc[mt][0] = __builtin_amdgcn_mfma_i32_16x16x64_i8(a1, breg[tp][1][0], acc[mt][0], 0, 0, 0);
                acc[mt][1] = __builtin_amdgcn_mfma_i32_16x16x64_i8(a1, breg[tp][1][1], acc[mt][1], 0, 0, 0);
            }
        }

        // ---- epilogue: requant + 14 direct v4i stores (after the 12 loads) ----
        const int m0 = s * 224 + mh * 112;
        #pragma unroll
        for (int mt = 0; mt < 7; ++mt) {
            #pragma unroll
            for (int ct = 0; ct < 2; ++ct) {
                v4i vv;
                #pragma unroll
                for (int i = 0; i < 4; ++i) {       // C/D row = quad*4+i
                    float yv = rintf((float)(acc[mt][ct][i] + bgv[ct]) * rs + zo);
                    yv = fminf(fmaxf(yv, -128.f), 127.f);
                    vv[i] = (int)yv;
                }
                *(v4i*)(out + (n * CO + cw + ct * 16 + lo16) * SPA +
                        m0 + mt * 16 + quad * 4) = vv;
            }
        }

        // ---- release: wait only for the 12 stage loads (14 newest = stores
        //      stay in flight), then barrier. No vmcnt(0) in the loop. ----
        if (t7 < 6) {
            __builtin_amdgcn_sched_barrier(0);
            asm volatile("s_waitcnt vmcnt(14)" ::: "memory");
            __builtin_amdgcn_s_barrier();
            __builtin_amdgcn_sched_barrier(0);
        }
    }
}

extern "C" void kernel_launch(void* const* d_in, const int* in_sizes, int n_in,
                              void* d_out, int out_size, void* d_ws, size_t ws_size,
                              hipStream_t stream) {
    const int*   x    = (const int*)d_in[0];
    const int*   wgt  = (const int*)d_in[1];
    const int*   bias = (const int*)d_in[2];
    const float* si   = (const float*)d_in[3];
    const float* sw   = (const float*)d_in[4];
    const float* so   = (const float*)d_in[5];
    const int*   zpi  = (const int*)d_in[6];
    const int*   zpo  = (const int*)d_in[7];
    int* out = (int*)d_out;

    int8_t* xp2 = (int8_t*)d_ws;
    int8_t* bp  = xp2 + XP2_BYTES;
    int*    bg  = (int*)(bp + BP_BYTES);

    prep_kernel<<<HH * NB + 2 * NB + CO, 256, 0, stream>>>(x, wgt, bias, zpi, xp2, bp, bg);
    qconv_mfma<<<256, 256, 0, stream>>>(xp2, bp, bg, si, sw, so, zpo, out);
}

// Round 3
// 180.736 us; speedup vs baseline: 1.1176x; 1.0370x over previous
//
#include <hip/hip_runtime.h>
#include <stdint.h>

// QuantizedConv2d int8 implicit GEMM via MFMA i32_16x16x64_i8.
// N=32, C_in=128, H=W=56, C_out=256, 3x3, pad 1, stride 1.
// Output int8 values stored as int32 (harness reads integer outputs as np.int32).
//
// R13: occupancy rework. R12 ran 1 block/CU (1 wave/SIMD) -> all latencies
// exposed (MfmaUtil 17%), and its 36-v4i B-panel didn't fit in registers
// (VGPR_Count 168 < needed ~230 -> remat/spill in the K-loop).
//  - 2-row slabs: 4 padded rows = 32 KB; LDS = 2x32 KB dbuf = 64 KB
//    -> 2 blocks/CU co-resident (2 waves/SIMD, independent barriers).
//  - 3584 tiles = 32 n x 28 slabs x 4 co64; 512 blocks x 7 tiles, balanced,
//    fully resident. XCD swizzle: bid&7 = XCD, 4 n-images per XCD (L2-res).
//  - Wave = 112 M x 16 co (7 mt x 1 ct): breg = 18 v4i (72 VGPR) -> fits.
//  - Async A dbuf: 8 global_load_lds issued before K-loop; released by
//    counted s_waitcnt vmcnt(7) (the 7 newest = this tile's stores stay in
//    flight) + raw s_barrier. No vmcnt(0) in the loop.

#define NB 32
#define CI 128
#define HH 56
#define WW 56
#define CO 256
#define SPA (HH * WW)              // 3136 = 28 slabs x 112 (2 image rows each)
#define HP 58
#define WP 64
#define XP2_BYTES (NB * HP * WP * CI)      // 15204352
#define BP_BYTES (9 * 2 * 4 * CO * 16)     // 294912
#define ABUF (4 * 8192)                    // 4 padded rows = 32 KB

typedef int v4i __attribute__((ext_vector_type(4)));

// ---- prep (unchanged from R10) ----
// [0,1792): pack one (n,h) row -> padded NHWC int8, pad byte = zp, XOR-swizzled
// [1792,1856): border h-rows = zp
// [1856,2112): weight pack + BG[co] = bias - zp*S9
__global__ __launch_bounds__(256) void prep_kernel(
    const int* __restrict__ x, const int* __restrict__ wgt,
    const int* __restrict__ bias, const int* __restrict__ zpi,
    int8_t* __restrict__ xp2, int8_t* __restrict__ bp, int* __restrict__ BG)
{
    __shared__ int sm[1824];
    const int tid = threadIdx.x, bid = blockIdx.x;
    const int zp = *zpi;
    const int zp4 = (zp & 255) * 0x01010101;

    if (bid < HH * NB) {
        const int n = bid / HH, h = bid % HH;
        #pragma unroll
        for (int it = 0; it < 7; ++it) {
            int j = tid + it * 256;                 // 1792 = 128 ci x 14 w4
            int ci = j / 14, w4 = j - ci * 14;
            const v4i v = *(const v4i*)(x + ((n * CI + ci) * HH + h) * WW + w4 * 4);
            sm[w4 * 130 + ci] = (v.x & 255) | ((v.y & 255) << 8) |
                                ((v.z & 255) << 16) | (v.w << 24);
        }
        __syncthreads();
        int* od = (int*)xp2 + (n * HP + h + 1) * (WP * CI / 4);  // 2048 dwords
        #pragma unroll
        for (int it = 0; it < 8; ++it) {
            int j = tid + it * 256;                 // j = widx*32 + ci4
            int widx = j >> 5, ci4 = j & 31;
            int val = zp4;                          // pad value = zp
            if (widx >= 1 && widx <= WW) {
                int w = widx - 1;
                int base = (w >> 2) * 130 + ci4 * 4;
                int sh = (w & 3) * 8;
                val = ((sm[base] >> sh) & 0xff) | (((sm[base+1] >> sh) & 0xff) << 8) |
                      (((sm[base+2] >> sh) & 0xff) << 16) | ((sm[base+3] >> sh) << 24);
            }
            od[j ^ ((widx & 7) << 2)] = val;        // XOR-swizzle 16-B units
        }
    } else if (bid < HH * NB + 2 * NB) {
        const int z = bid - HH * NB;
        const int n = z >> 1, hidx = (z & 1) ? (HP - 1) : 0;
        int* od = (int*)xp2 + (n * HP + hidx) * (WP * CI / 4);
        #pragma unroll
        for (int it = 0; it < 8; ++it) od[tid + it * 256] = zp4;  // zp border rows
    } else {
        const int co = bid - (HH * NB + 2 * NB);
        for (int j = tid; j < 1152; j += 256) sm[j] = wgt[co * 1152 + j];  // [ci][9]
        __syncthreads();
        for (int j = tid; j < 288; j += 256) {      // 9t x 2c64 x 4q x 4j4
            int j4 = j & 3, q = (j >> 2) & 3, c64 = (j >> 4) & 1, t = j >> 5;
            int ci = c64 * 64 + q * 16 + j4 * 4;
            int b0 = sm[(ci + 0) * 9 + t] & 255, b1 = sm[(ci + 1) * 9 + t] & 255;
            int b2 = sm[(ci + 2) * 9 + t] & 255, b3 = sm[(ci + 3) * 9 + t];
            ((int*)bp)[((t * 2 + c64) * 4 + q) * 1024 + co * 4 + j4] =
                b0 | (b1 << 8) | (b2 << 16) | (b3 << 24);
        }
        if (tid < 9) {
            int s = 0;
            for (int ci = 0; ci < CI; ++ci) s += sm[ci * 9 + tid];
            sm[1152 + tid] = s;
        }
        __syncthreads();
        if (tid == 0) {
            int s9 = 0;
            for (int t = 0; t < 9; ++t) s9 += sm[1152 + t];
            BG[co] = bias[co] - zp * s9;            // cls-independent correction
        }
    }
}

// ---- main: 512 blocks x 256 thr, 2 blocks/CU; block = (n, co64, group) ----
__global__ __launch_bounds__(256, 2) void qconv_mfma(
    const int8_t* __restrict__ xp2, const int8_t* __restrict__ bp,
    const int* __restrict__ BG,
    const float* __restrict__ si, const float* __restrict__ sw,
    const float* __restrict__ so, const int* __restrict__ zpo,
    int* __restrict__ out)
{
    const int tid  = threadIdx.x, lane = tid & 63, wid = tid >> 6;
    const int quad = lane >> 4, lo16 = lane & 15;
    const int bid  = blockIdx.x;                    // 512 blocks, 2 per CU
    const int x    = bid & 7, r = bid >> 3;         // x = XCD
    const int n    = x * 4 + (r & 3);               // 4 n-images per XCD
    const int co64 = (r >> 2) & 3;
    const int g    = r >> 4;                        // slab group 0..3
    const int cw   = co64 * 64 + wid * 16;          // wave co base (16 co)

    __shared__ __attribute__((aligned(16))) int8_t Asm[2][ABUF];  // 64 KB

    // ---- prologue: stage slab g (4 padded rows, 32 KB) into buf0 ----
    const int8_t* src0 = xp2 + (((size_t)n * HP + 2 * g) << 13);
    #pragma unroll
    for (int k = 0; k < 8; ++k) {
        const int u = wid + 4 * k;                  // 32 x 1-KB units
        __builtin_amdgcn_global_load_lds(
            (const __attribute__((address_space(1))) void*)(src0 + (u << 10) + lane * 16),
            (__attribute__((address_space(3))) void*)(&Asm[0][u << 10]), 16, 0, 0);
    }

    // ---- B -> registers: breg[tap][c64], 18 v4i (72 VGPR, fits) ----
    v4i breg[9][2];
    #pragma unroll
    for (int t = 0; t < 9; ++t)
        #pragma unroll
        for (int c = 0; c < 2; ++c)
            breg[t][c] = *(const v4i*)(bp + (((t * 2 + c) * 4 + quad) << 12) +
                                       (cw + lo16) * 16);

    const int bg0 = BG[cw + lo16];
    const float rs = (*si) * (*sw) / (*so);
    const float zo = (float)(*zpo);

    // per-mt geometry (slab-local): row offset + swizzled col part per tap-col
    int rowoff[7], colp[7][3];
    #pragma unroll
    for (int mt = 0; mt < 7; ++mt) {
        const int ml = mt * 16 + lo16;              // 0..111 within slab
        const int srow = ml / 56, scol = ml - srow * 56;
        rowoff[mt] = srow * 8192;
        #pragma unroll
        for (int dc = 0; dc < 3; ++dc) {
            const int c2 = scol + dc;               // padded col 0..57
            colp[mt][dc] = (c2 * 128 + quad * 16) ^ ((c2 & 7) << 4);
        }
    }

    int* optr = out + ((size_t)n * CO + cw + lo16) * SPA + quad * 4;

    __syncthreads();                                // prologue drained (vmcnt(0) ok here)

    #pragma unroll 1
    for (int t7 = 0; t7 < 7; ++t7) {
        const int s = g + 4 * t7;                   // slab 0..27
        const int8_t* curA = Asm[t7 & 1];

        // ---- issue async stage of slab s+4 into the idle buffer ----
        if (t7 < 6) {
            const int8_t* srcn = xp2 + (((size_t)n * HP + 2 * (s + 4)) << 13);
            int8_t* dst = (int8_t*)Asm[(t7 & 1) ^ 1];
            #pragma unroll
            for (int k = 0; k < 8; ++k) {
                const int u = wid + 4 * k;
                __builtin_amdgcn_global_load_lds(
                    (const __attribute__((address_space(1))) void*)(srcn + (u << 10) + lane * 16),
                    (__attribute__((address_space(3))) void*)(dst + (u << 10)), 16, 0, 0);
            }
        }
        __builtin_amdgcn_sched_barrier(0);          // pin load issue before K-loop

        v4i acc[7];
        #pragma unroll
        for (int mt = 0; mt < 7; ++mt) acc[mt] = (v4i){0, 0, 0, 0};

        // ---- K-loop: 9 taps x 7 mt x (2 reads + 2 MFMA) ----
        #pragma unroll
        for (int tp = 0; tp < 9; ++tp) {
            const int dr = tp / 3, dc = tp % 3;
            #pragma unroll
            for (int mt = 0; mt < 7; ++mt) {
                const int off = rowoff[mt] + dr * 8192 + colp[mt][dc];
                v4i a0 = *(const v4i*)(curA + off);          // logical ci 0..63
                v4i a1 = *(const v4i*)(curA + (off ^ 64));   // logical +64 -> phys^64
                acc[mt] = __builtin_amdgcn_mfma_i32_16x16x64_i8(a0, breg[tp][0], acc[mt], 0, 0, 0);
                acc[mt] = __builtin_amdgcn_mfma_i32_16x16x64_i8(a1, breg[tp][1], acc[mt], 0, 0, 0);
            }
        }

        // ---- epilogue: requant + 7 direct v4i stores (after the 8 loads) ----
        const int m0 = s * 112;
        #pragma unroll
        for (int mt = 0; mt < 7; ++mt) {
            v4i vv;
            #pragma unroll
            for (int i = 0; i < 4; ++i) {           // C/D row = quad*4+i
                float yv = rintf((float)(acc[mt][i] + bg0) * rs + zo);
                yv = fminf(fmaxf(yv, -128.f), 127.f);
                vv[i] = (int)yv;
            }
            *(v4i*)(optr + m0 + mt * 16) = vv;
        }

        // ---- release: wait only for the 8 stage loads (7 newest = stores
        //      stay in flight), then barrier. No vmcnt(0) in the loop. ----
        if (t7 < 6) {
            __builtin_amdgcn_sched_barrier(0);
            asm volatile("s_waitcnt vmcnt(7)" ::: "memory");
            __builtin_amdgcn_s_barrier();
            __builtin_amdgcn_sched_barrier(0);
        }
    }
}

extern "C" void kernel_launch(void* const* d_in, const int* in_sizes, int n_in,
                              void* d_out, int out_size, void* d_ws, size_t ws_size,
                              hipStream_t stream) {
    const int*   x    = (const int*)d_in[0];
    const int*   wgt  = (const int*)d_in[1];
    const int*   bias = (const int*)d_in[2];
    const float* si   = (const float*)d_in[3];
    const float* sw   = (const float*)d_in[4];
    const float* so   = (const float*)d_in[5];
    const int*   zpi  = (const int*)d_in[6];
    const int*   zpo  = (const int*)d_in[7];
    int* out = (int*)d_out;

    int8_t* xp2 = (int8_t*)d_ws;
    int8_t* bp  = xp2 + XP2_BYTES;
    int*    bg  = (int*)(bp + BP_BYTES);

    prep_kernel<<<HH * NB + 2 * NB + CO, 256, 0, stream>>>(x, wgt, bias, zpi, xp2, bp, bg);
    qconv_mfma<<<512, 256, 0, stream>>>(xp2, bp, bg, si, sw, so, zpo, out);
}